// Round 1
// baseline (8747.840 us; speedup 1.0000x reference)
//
#include <hip/hip_runtime.h>
#include <math.h>

#define W_WIN 5
#define NSUB 2
#define MAX_SEG 64
#define MAX_T 256

__device__ __forceinline__ float softplusf(float v) {
    // jax.nn.softplus == logaddexp(v, 0) == max(v,0) + log1p(exp(-|v|))
    return fmaxf(v, 0.0f) + log1pf(expf(-fabsf(v)));
}

// numpy pairwise-sum order for n=128: 8 strided accumulators, then
// ((r0+r1)+(r2+r3)) + ((r4+r5)+(r6+r7)).  red must have >= 9 slots.
__device__ float block_sum128_np(const float* a, float* red, int tid) {
    if (tid < 8) {
        float s = a[tid];
        #pragma unroll
        for (int m = 1; m < 16; ++m) s += a[tid + 8 * m];
        red[tid] = s;
    }
    __syncthreads();
    if (tid == 0) {
        red[8] = ((red[0] + red[1]) + (red[2] + red[3])) +
                 ((red[4] + red[5]) + (red[6] + red[7]));
    }
    __syncthreads();
    float r = red[8];
    __syncthreads();
    return r;
}

__device__ float block_max128(const float* a, float* red, int tid) {
    if (tid < 8) {
        float mx = a[tid];
        for (int k = tid + 8; k < 128; k += 8) mx = fmaxf(mx, a[k]);
        red[tid] = mx;
    }
    __syncthreads();
    if (tid == 0) {
        float mx = red[0];
        for (int k = 1; k < 8; ++k) mx = fmaxf(mx, red[k]);
        red[8] = mx;
    }
    __syncthreads();
    float r = red[8];
    __syncthreads();
    return r;
}

// insert v into sorted cand[0..m), dedupe exact equality (mirrors sorted(set(...)))
__device__ void ins_sorted_dedupe(double* cand, int* m, double v) {
    int p = 0;
    while (p < *m && cand[p] < v) ++p;
    if (p < *m && cand[p] == v) return;
    for (int k = *m; k > p; --k) cand[k] = cand[k - 1];
    cand[p] = v;
    (*m)++;
}

// ---------------- kernel 1: encoder (also writes traj_t output block) ----------------
__global__ void encode_kernel(const float* __restrict__ emb, const int* __restrict__ hi,
                              const float* __restrict__ w1, const float* __restrict__ b1,
                              const float* __restrict__ w2, const float* __restrict__ b2,
                              float* __restrict__ enc, float* __restrict__ out,
                              int B, int L, int D) {
    __shared__ float x[128];
    __shared__ float h[128];
    int row = blockIdx.x;           // 0 .. B*L-1
    int j = threadIdx.x;            // 0 .. D-1
    int idx = hi[row];
    x[j] = emb[(size_t)idx * D + j];
    __syncthreads();
    float s = b1[j];
    #pragma unroll 8
    for (int i = 0; i < 128; ++i) s += x[i] * w1[i * 128 + j];
    h[j] = fmaxf(s, 0.0f);
    __syncthreads();
    float o = b2[j];
    #pragma unroll 8
    for (int i = 0; i < 128; ++i) o += h[i] * w2[i * 128 + j];
    enc[(size_t)row * D + j] = o;
    int b = row / L, l = row % L;
    size_t OS = 2 + 2 * (size_t)L * D;
    out[(size_t)b * OS + 2 + (size_t)L * D + (size_t)l * D + j] = o;
}

// ---------------- kernel 2: APT partition + plan building (1 block / batch) ----------------
__global__ void plan_kernel(const float* __restrict__ enc_all, const float* __restrict__ ht,
                            const int* __restrict__ hl, const float* __restrict__ pt,
                            float* __restrict__ envs, float* __restrict__ dt_sched,
                            int* __restrict__ envid, int* __restrict__ stateidx,
                            int* __restrict__ Tcnt, int B, int L, int D) {
    int b = blockIdx.x;
    int tid = threadIdx.x;          // 0..127
    const float* enc = enc_all + (size_t)b * L * D;
    const float* times = ht + (size_t)b * L;
    int n = hl[b];

    __shared__ float ml[128], mr[128], qa[128], qb[128];
    __shared__ float red[9];
    __shared__ int jj, nb_s, ns_s;
    __shared__ double bounds[40];
    __shared__ int starts[40];
    __shared__ int seg_s[MAX_SEG], seg_e[MAX_SEG];
    __shared__ double cand[160];

    if (tid == 0) {
        jj = 0; nb_s = 1; ns_s = 1;
        bounds[0] = (double)times[0];
        starts[0] = 0;
    }
    __syncthreads();

    if (n >= 2 * W_WIN) {
        while (true) {
            __syncthreads();
            int j = jj;
            if (j > n - 2 * W_WIN) break;
            int i = tid;
            // window means (numpy axis-0 reduce: sequential left fold, then /5)
            {
                float a0 = enc[(j + 0) * D + i], a1 = enc[(j + 1) * D + i];
                float a2 = enc[(j + 2) * D + i], a3 = enc[(j + 3) * D + i];
                float a4 = enc[(j + 4) * D + i];
                ml[i] = ((((a0 + a1) + a2) + a3) + a4) / 5.0f;
                float c0 = enc[(j + 5) * D + i], c1 = enc[(j + 6) * D + i];
                float c2 = enc[(j + 7) * D + i], c3 = enc[(j + 8) * D + i];
                float c4 = enc[(j + 9) * D + i];
                mr[i] = ((((c0 + c1) + c2) + c3) + c4) / 5.0f;
            }
            __syncthreads();
            // softmax left
            float mxl = block_max128(ml, red, tid);
            qa[i] = expf(ml[i] - mxl);
            __syncthreads();
            float sl = block_sum128_np(qa, red, tid);
            float plv = qa[i] / sl;
            // softmax right
            float mxr = block_max128(mr, red, tid);
            qb[i] = expf(mr[i] - mxr);
            __syncthreads();
            float sr = block_sum128_np(qb, red, tid);
            float prv = qb[i] / sr;
            // jsd
            qa[i] = plv + 1e-8f;
            __syncthreads();
            float sp = block_sum128_np(qa, red, tid);
            float pv = qa[i] / sp;
            qb[i] = prv + 1e-8f;
            __syncthreads();
            float sq = block_sum128_np(qb, red, tid);
            float qv = qb[i] / sq;
            float mv = 0.5f * (pv + qv);
            qa[i] = pv * logf(pv / mv);
            qb[i] = qv * logf(qv / mv);
            __syncthreads();
            float s1 = block_sum128_np(qa, red, tid);
            float s2 = block_sum128_np(qb, red, tid);
            float jsd = 0.5f * s1 + 0.5f * s2;
            if (tid == 0) {
                if (jsd > 0.5f) {
                    if (nb_s < 39 && ns_s < 39) {
                        bounds[nb_s++] = ((double)times[j + W_WIN - 1] + (double)times[j + W_WIN]) * 0.5;
                        starts[ns_s++] = j + W_WIN;
                    }
                    jj = j + W_WIN;
                } else {
                    jj = j + 1;
                }
            }
        }
    }
    __syncthreads();

    if (tid == 0) {
        int nb = nb_s, ns = ns_s;
        if ((double)times[n - 1] > bounds[nb - 1]) bounds[nb++] = (double)times[n - 1];
        for (int si = 0; si < ns; ++si) {
            seg_s[si] = starts[si];
            seg_e[si] = (si + 1 < ns) ? (starts[si + 1] - 1) : (n - 1);
        }
        int C = 0;
        for (int si = 0; si < ns; ++si) {
            double t0 = bounds[si];
            double t1 = (si + 1 < nb) ? bounds[si + 1] : bounds[nb - 1];
            int m = 0;
            cand[m++] = t0;
            ins_sorted_dedupe(cand, &m, t1);
            for (int l = seg_s[si]; l <= seg_e[si]; ++l) {
                double tv = (double)times[l];
                if (tv >= t0 && tv <= t1) ins_sorted_dedupe(cand, &m, tv);
            }
            // _make_increasing (float64, gap 1e-6)
            for (int k = 1; k < m; ++k)
                if (cand[k] - cand[k - 1] < 1e-6) cand[k] = cand[k - 1] + 1e-6;
            int K = m - 1;
            if (C + K > MAX_T) K = MAX_T - C;   // safety clamp
            for (int k = 0; k < K; ++k) {
                dt_sched[b * MAX_T + C + k] = (float)(cand[k + 1] - cand[k]);
                envid[b * MAX_T + C + k] = si;
            }
            for (int l = seg_s[si]; l <= seg_e[si]; ++l) {
                double tv = (double)times[l];
                int best = 0;
                double bd = fabs(cand[0] - tv);
                for (int k = 1; k < m; ++k) {
                    double dk = fabs(cand[k] - tv);
                    if (dk < bd) { bd = dk; best = k; }
                }
                stateidx[b * L + l] = C + best;
            }
            C += K;
        }
        double ptv = (double)pt[b];
        if (ptv > bounds[nb - 1] + 1e-6 && C < MAX_T) {
            double a0d = bounds[nb - 1], a1d = ptv;
            if (a1d - a0d < 1e-6) a1d = a0d + 1e-6;
            dt_sched[b * MAX_T + C] = (float)(a1d - a0d);
            envid[b * MAX_T + C] = ns - 1;
            C++;
        }
        Tcnt[b] = C;
        ns_s = ns;
    }
    __syncthreads();
    // per-segment env = mean of encoded rows (parallel over dim)
    int ns = ns_s;
    for (int si = 0; si < ns; ++si) {
        int s = seg_s[si], e = seg_e[si];
        float sum = 0.0f;
        for (int l = s; l <= e; ++l) sum += enc[(size_t)l * D + tid];
        envs[((size_t)b * MAX_SEG + si) * D + tid] = sum / (float)(e - s + 1);
    }
}

// ---------------- kernel 3: sequential Euler ODE chain (1 block / batch) ----------------
__global__ __launch_bounds__(512) void ode_kernel(
    const float* __restrict__ usert, const int* __restrict__ u,
    const float* __restrict__ w1, const float* __restrict__ b1,
    const float* __restrict__ w2, const float* __restrict__ b2,
    const float* __restrict__ w3, const float* __restrict__ b3,
    const float* __restrict__ emb, const int* __restrict__ pos, const int* __restrict__ neg,
    const float* __restrict__ envs, const float* __restrict__ dt_sched,
    const int* __restrict__ envid, const int* __restrict__ stateidx,
    const int* __restrict__ Tcnt,
    float* __restrict__ out, int B, int L, int D, int H) {
    int b = blockIdx.x;
    int tid = threadIdx.x;          // 0..511
    __shared__ float x[256];        // [z | env]
    __shared__ float h1[512];
    __shared__ float h2[512];
    __shared__ int sidx[128];
    size_t OS = 2 + 2 * (size_t)L * D;
    float* outb = out + (size_t)b * OS;

    if (tid < D) x[tid] = usert[(size_t)u[b] * D + tid];
    if (tid < L) sidx[tid] = stateidx[b * L + tid];
    __syncthreads();
    int T = Tcnt[b];
    int l_ptr = 0;
    // record initial state (m = 0)
    while (l_ptr < L && sidx[l_ptr] == 0) {
        if (tid < D) outb[2 + (size_t)l_ptr * D + tid] = x[tid];
        ++l_ptr;
    }
    for (int t = 0; t < T; ++t) {
        int si = envid[b * MAX_T + t];
        float dt = dt_sched[b * MAX_T + t];
        float hdt = dt * (1.0f / (float)NSUB);
        const float* env = envs + ((size_t)b * MAX_SEG + si) * D;
        if (tid < D) x[D + tid] = env[tid];
        for (int sub = 0; sub < NSUB; ++sub) {
            __syncthreads();
            // layer 1: (256 -> 512)
            float s1v = b1[tid];
            #pragma unroll 8
            for (int i = 0; i < 256; ++i) s1v += x[i] * w1[i * 512 + tid];
            h1[tid] = softplusf(s1v);
            __syncthreads();
            // layer 2: (512 -> 512)
            float s2v = b2[tid];
            #pragma unroll 8
            for (int i = 0; i < 512; ++i) s2v += h1[i] * w2[i * 512 + tid];
            h2[tid] = softplusf(s2v);
            __syncthreads();
            // layer 3: (512 -> 128) + Euler update
            if (tid < D) {
                float s3v = b3[tid];
                #pragma unroll 8
                for (int i = 0; i < 512; ++i) s3v += h2[i] * w3[i * 128 + tid];
                x[tid] = x[tid] + hdt * s3v;
            }
        }
        int m = t + 1;
        while (l_ptr < L && sidx[l_ptr] == m) {
            if (tid < D) outb[2 + (size_t)l_ptr * D + tid] = x[tid];
            ++l_ptr;
        }
    }
    __syncthreads();
    // scores
    if (tid < D) {
        float zv = x[tid];
        h1[tid] = zv * emb[(size_t)pos[b] * D + tid];
        h2[tid] = zv * emb[(size_t)neg[b] * D + tid];
    }
    __syncthreads();
    if (tid == 0) {
        float sp = 0.0f, sn = 0.0f;
        for (int i = 0; i < D; ++i) { sp += h1[i]; sn += h2[i]; }
        outb[0] = sp;
        outb[1] = sn;
    }
}

extern "C" void kernel_launch(void* const* d_in, const int* in_sizes, int n_in,
                              void* d_out, int out_size, void* d_ws, size_t ws_size,
                              hipStream_t stream) {
    const float* emb   = (const float*)d_in[0];
    const float* w1    = (const float*)d_in[1];
    const float* b1    = (const float*)d_in[2];
    const float* w2    = (const float*)d_in[3];
    const float* b2    = (const float*)d_in[4];
    const float* usert = (const float*)d_in[5];
    const float* vw1   = (const float*)d_in[6];
    const float* vb1   = (const float*)d_in[7];
    const float* vw2   = (const float*)d_in[8];
    const float* vb2   = (const float*)d_in[9];
    const float* vw3   = (const float*)d_in[10];
    const float* vb3   = (const float*)d_in[11];
    const int*   u     = (const int*)d_in[12];
    const int*   hi    = (const int*)d_in[13];
    const float* ht    = (const float*)d_in[14];
    const int*   hl    = (const int*)d_in[15];
    const int*   pos   = (const int*)d_in[16];
    const int*   neg   = (const int*)d_in[17];
    const float* pt    = (const float*)d_in[18];

    int D = in_sizes[2];         // 128
    int H = in_sizes[7];         // 512
    int B = in_sizes[12];        // 4
    int L = in_sizes[13] / B;    // 128

    // workspace carve-up
    float* ws       = (float*)d_ws;
    float* enc      = ws;                                  // B*L*D
    float* envs     = enc + (size_t)B * L * D;             // B*MAX_SEG*D
    float* dt_sched = envs + (size_t)B * MAX_SEG * D;      // B*MAX_T
    int*   envid    = (int*)(dt_sched + (size_t)B * MAX_T);// B*MAX_T
    int*   stateidx = envid + (size_t)B * MAX_T;           // B*L
    int*   Tcnt     = stateidx + (size_t)B * L;            // B

    encode_kernel<<<B * L, D, 0, stream>>>(emb, hi, w1, b1, w2, b2, enc, (float*)d_out, B, L, D);
    plan_kernel<<<B, D, 0, stream>>>(enc, ht, hl, pt, envs, dt_sched, envid, stateidx, Tcnt, B, L, D);
    ode_kernel<<<B, H, 0, stream>>>(usert, u, vw1, vb1, vw2, vb2, vw3, vb3, emb, pos, neg,
                                    envs, dt_sched, envid, stateidx, Tcnt,
                                    (float*)d_out, B, L, D, H);
}

// Round 2
// 6353.444 us; speedup vs baseline: 1.3769x; 1.3769x over previous
//
#include <hip/hip_runtime.h>
#include <math.h>

#define W_WIN 5
#define NSUB 2
#define MAX_SEG 64
#define MAX_T 256
#define NWG 32

__device__ __forceinline__ float softplusf(float v) {
    // jax.nn.softplus == logaddexp(v, 0) == max(v,0) + log1p(exp(-|v|))
    return fmaxf(v, 0.0f) + log1pf(expf(-fabsf(v)));
}

// ---------------- numpy-faithful fused reductions (plan kernel) ----------------
// numpy pairwise sum, n=128: r_k = a[k]+a[k+8]+...+a[k+120] (serial left fold),
// then ((r0+r1)+(r2+r3)) + ((r4+r5)+(r6+r7)).
__device__ void sum2_np(const float* a, const float* b, float* red, int tid,
                        float* oa, float* ob) {
    if (tid < 16) {
        const float* src = (tid < 8) ? a : b;
        int k = tid & 7;
        float s = src[k];
        #pragma unroll
        for (int m = 1; m < 16; ++m) s += src[k + 8 * m];
        red[tid] = s;
    }
    __syncthreads();
    if (tid == 0) {
        red[16] = ((red[0] + red[1]) + (red[2] + red[3])) +
                  ((red[4] + red[5]) + (red[6] + red[7]));
        red[17] = ((red[8] + red[9]) + (red[10] + red[11])) +
                  ((red[12] + red[13]) + (red[14] + red[15]));
    }
    __syncthreads();
    *oa = red[16];
    *ob = red[17];
    __syncthreads();
}

__device__ void max2_np(const float* a, const float* b, float* red, int tid,
                        float* oa, float* ob) {
    if (tid < 16) {
        const float* src = (tid < 8) ? a : b;
        int k = tid & 7;
        float mx = src[k];
        for (int q = k + 8; q < 128; q += 8) mx = fmaxf(mx, src[q]);
        red[tid] = mx;
    }
    __syncthreads();
    if (tid == 0) {
        float m0 = red[0], m1 = red[8];
        for (int k = 1; k < 8; ++k) { m0 = fmaxf(m0, red[k]); m1 = fmaxf(m1, red[8 + k]); }
        red[16] = m0; red[17] = m1;
    }
    __syncthreads();
    *oa = red[16];
    *ob = red[17];
    __syncthreads();
}

// ---------------- kernel 1: encoder (also writes traj_t output block) ----------------
__global__ void encode_kernel(const float* __restrict__ emb, const int* __restrict__ hi,
                              const float* __restrict__ w1, const float* __restrict__ b1,
                              const float* __restrict__ w2, const float* __restrict__ b2,
                              float* __restrict__ enc, float* __restrict__ out,
                              int B, int L, int D) {
    __shared__ float x[128];
    __shared__ float h[128];
    int row = blockIdx.x;           // 0 .. B*L-1
    int j = threadIdx.x;            // 0 .. D-1
    int idx = hi[row];
    x[j] = emb[(size_t)idx * D + j];
    __syncthreads();
    float s = b1[j];
    #pragma unroll 8
    for (int i = 0; i < 128; ++i) s += x[i] * w1[i * 128 + j];
    h[j] = fmaxf(s, 0.0f);
    __syncthreads();
    float o = b2[j];
    #pragma unroll 8
    for (int i = 0; i < 128; ++i) o += h[i] * w2[i * 128 + j];
    enc[(size_t)row * D + j] = o;
    int b = row / L, l = row % L;
    size_t OS = 2 + 2 * (size_t)L * D;
    out[(size_t)b * OS + 2 + (size_t)L * D + (size_t)l * D + j] = o;
}

// ---------------- kernel 2: APT partition + plan building (1 block / batch) ----------------
__global__ void plan_kernel(const float* __restrict__ enc_all, const float* __restrict__ ht,
                            const int* __restrict__ hl, const float* __restrict__ pt,
                            float* __restrict__ envs, float* __restrict__ dt_sched,
                            int* __restrict__ envid, int* __restrict__ stateidx,
                            int* __restrict__ Tcnt, int B, int L, int D) {
    int b = blockIdx.x;
    int tid = threadIdx.x;          // 0..127
    const float* enc = enc_all + (size_t)b * L * D;
    const float* times = ht + (size_t)b * L;
    int n = hl[b];

    __shared__ float ml[128], mr[128], qa[128], qb[128];
    __shared__ float red[18];
    __shared__ int jj, nb_s, ns_s;
    __shared__ double bounds[40];
    __shared__ int starts[40];
    __shared__ int seg_s[MAX_SEG], seg_e[MAX_SEG];
    __shared__ double cand[160];
    __shared__ int m_sh, cbase_sh, s_sh, e_sh;

    if (tid == 0) {
        jj = 0; nb_s = 1; ns_s = 1;
        bounds[0] = (double)times[0];
        starts[0] = 0;
    }
    __syncthreads();

    if (n >= 2 * W_WIN) {
        while (true) {
            __syncthreads();
            int j = jj;
            if (j > n - 2 * W_WIN) break;
            int i = tid;
            // window means (numpy axis-0 reduce: sequential left fold, then /5)
            {
                float a0 = enc[(j + 0) * D + i], a1 = enc[(j + 1) * D + i];
                float a2 = enc[(j + 2) * D + i], a3 = enc[(j + 3) * D + i];
                float a4 = enc[(j + 4) * D + i];
                ml[i] = ((((a0 + a1) + a2) + a3) + a4) / 5.0f;
                float c0 = enc[(j + 5) * D + i], c1 = enc[(j + 6) * D + i];
                float c2 = enc[(j + 7) * D + i], c3 = enc[(j + 8) * D + i];
                float c4 = enc[(j + 9) * D + i];
                mr[i] = ((((c0 + c1) + c2) + c3) + c4) / 5.0f;
            }
            __syncthreads();
            float mxl, mxr;
            max2_np(ml, mr, red, tid, &mxl, &mxr);
            qa[i] = expf(ml[i] - mxl);
            qb[i] = expf(mr[i] - mxr);
            __syncthreads();
            float sl, sr;
            sum2_np(qa, qb, red, tid, &sl, &sr);
            // p = softmax + 1e-8 ; q likewise
            qa[i] = qa[i] / sl + 1e-8f;
            qb[i] = qb[i] / sr + 1e-8f;
            __syncthreads();
            float sp, sq;
            sum2_np(qa, qb, red, tid, &sp, &sq);
            float pv = qa[i] / sp;
            float qv = qb[i] / sq;
            float mv = 0.5f * (pv + qv);
            qa[i] = pv * logf(pv / mv);
            qb[i] = qv * logf(qv / mv);
            __syncthreads();
            float s1, s2;
            sum2_np(qa, qb, red, tid, &s1, &s2);
            float jsd = 0.5f * s1 + 0.5f * s2;
            if (tid == 0) {
                if (jsd > 0.5f) {
                    if (nb_s < 39 && ns_s < 39) {
                        bounds[nb_s++] = ((double)times[j + W_WIN - 1] + (double)times[j + W_WIN]) * 0.5;
                        starts[ns_s++] = j + W_WIN;
                    }
                    jj = j + W_WIN;
                } else {
                    jj = j + 1;
                }
            }
        }
    }
    __syncthreads();

    // segment boundaries (serial, tiny)
    if (tid == 0) {
        int nb = nb_s, ns = ns_s;
        if ((double)times[n - 1] > bounds[nb - 1]) bounds[nb++] = (double)times[n - 1];
        nb_s = nb;
        for (int si = 0; si < ns; ++si) {
            seg_s[si] = starts[si];
            seg_e[si] = (si + 1 < ns) ? (starts[si + 1] - 1) : (n - 1);
        }
        cbase_sh = 0;
    }
    __syncthreads();
    int ns = ns_s, nb = nb_s;

    for (int si = 0; si < ns; ++si) {
        if (tid == 0) {
            double t0 = bounds[si];
            double t1 = (si + 1 < nb) ? bounds[si + 1] : bounds[nb - 1];
            int s = seg_s[si], e = seg_e[si];
            // linear merge build of sorted(set([t0,t1] + in-range times)):
            // times are sorted, t0 <= times[s], t1 >= times[e]  -> O(m)
            int m = 0;
            cand[m++] = t0;
            for (int l = s; l <= e; ++l) {
                double tv = (double)times[l];
                if (tv < t0 || tv > t1) continue;
                if (tv != cand[m - 1]) cand[m++] = tv;
            }
            if (t1 > cand[m - 1]) cand[m++] = t1;
            // _make_increasing (float64, gap 1e-6)
            for (int k = 1; k < m; ++k)
                if (cand[k] - cand[k - 1] < 1e-6) cand[k] = cand[k - 1] + 1e-6;
            m_sh = m; s_sh = s; e_sh = e;
        }
        __syncthreads();
        int m = m_sh, s = s_sh, e = e_sh, C = cbase_sh;
        int K = m - 1;
        if (C + K > MAX_T) K = MAX_T - C;   // safety clamp
        for (int k = tid; k < K; k += 128) {
            dt_sched[b * MAX_T + C + k] = (float)(cand[k + 1] - cand[k]);
            envid[b * MAX_T + C + k] = si;
        }
        for (int l = s + tid; l <= e; l += 128) {
            double tv = (double)times[l];
            int best = 0;
            double bd = fabs(cand[0] - tv);
            for (int k = 1; k < m; ++k) {
                double dk = fabs(cand[k] - tv);
                if (dk < bd) { bd = dk; best = k; }
            }
            stateidx[b * L + l] = C + best;
        }
        __syncthreads();
        if (tid == 0) cbase_sh = C + K;
        __syncthreads();
    }

    if (tid == 0) {
        int C = cbase_sh;
        double ptv = (double)pt[b];
        if (ptv > bounds[nb - 1] + 1e-6 && C < MAX_T) {
            double a0d = bounds[nb - 1], a1d = ptv;
            if (a1d - a0d < 1e-6) a1d = a0d + 1e-6;
            dt_sched[b * MAX_T + C] = (float)(a1d - a0d);
            envid[b * MAX_T + C] = ns - 1;
            C++;
        }
        Tcnt[b] = C;
    }
    __syncthreads();
    // per-segment env = mean of encoded rows (parallel over dim)
    for (int si = 0; si < ns; ++si) {
        int s = seg_s[si], e = seg_e[si];
        float sum = 0.0f;
        for (int l = s; l <= e; ++l) sum += enc[(size_t)l * D + tid];
        envs[((size_t)b * MAX_SEG + si) * D + tid] = sum / (float)(e - s + 1);
    }
}

// ---------------- device-scope phase barrier across NWG workgroups ----------------
__device__ __forceinline__ void gbar(int* cnt, int phase) {
    __syncthreads();
    if (threadIdx.x == 0) {
        __threadfence();
        __hip_atomic_fetch_add(cnt, 1, __ATOMIC_RELEASE, __HIP_MEMORY_SCOPE_AGENT);
        const int target = phase * NWG;
        while (__hip_atomic_load(cnt, __ATOMIC_ACQUIRE, __HIP_MEMORY_SCOPE_AGENT) < target) {
            __builtin_amdgcn_s_sleep(1);
        }
        __threadfence();
    }
    __syncthreads();
}

// ---------------- kernel 3: cooperative ODE chain, weights LDS-resident ----------------
// 32 WGs x 256 threads. WG g owns cols [g*16, g*16+16) of h1/h2 and
// cols [g*4, g*4+4) of z. All 4 batches advanced in lockstep (shared weights).
__global__ __launch_bounds__(256) void ode_coop(
    const float* __restrict__ usert, const int* __restrict__ u,
    const float* __restrict__ vw1, const float* __restrict__ vb1,
    const float* __restrict__ vw2, const float* __restrict__ vb2,
    const float* __restrict__ vw3, const float* __restrict__ vb3,
    const float* __restrict__ emb, const int* __restrict__ pos, const int* __restrict__ neg,
    const float* __restrict__ envs, const float* __restrict__ dtsch,
    const int* __restrict__ envid, const int* __restrict__ stidx,
    const int* __restrict__ Tc,
    float* __restrict__ zg, float* __restrict__ h1g, float* __restrict__ h2g,
    int* __restrict__ cnt, float* __restrict__ out)
{
    const int g = blockIdx.x;       // 0..31
    const int tid = threadIdx.x;    // 0..255
    __shared__ __align__(16) float w1s[16 * 256];   // [c][i], col slice of vf_w1
    __shared__ __align__(16) float w2s[16 * 512];   // [c][i]
    __shared__ __align__(16) float stage[4 * 512];  // [b][i] : x (256) / h1 / h2
    __shared__ int sidx_sh[512];                    // [b][l]
    const size_t OS = 2 + 2 * (size_t)128 * 128;    // per-batch out row

    // preload weight slices into LDS (once)
    {
        int c = tid & 15, il = tid >> 4;    // il 0..15
        for (int r = 0; r < 16; ++r) {
            int i = r * 16 + il;
            w1s[c * 256 + i] = vw1[(size_t)i * 512 + g * 16 + c];
        }
        for (int r = 0; r < 32; ++r) {
            int i = r * 16 + il;
            w2s[c * 512 + i] = vw2[(size_t)i * 512 + g * 16 + c];
        }
    }
    const int c3 = tid >> 6, p3 = tid & 63;     // L3 mapping: 4 cols x 64 lanes
    const int gcol = g * 4 + c3;
    float w3r[8];
    #pragma unroll
    for (int j = 0; j < 8; ++j) w3r[j] = vw3[(size_t)(p3 * 8 + j) * 128 + gcol];
    for (int idx = tid; idx < 512; idx += 256) sidx_sh[idx] = stidx[idx];

    int Tb[4];
    #pragma unroll
    for (int b = 0; b < 4; ++b) Tb[b] = Tc[b];
    int maxT = max(max(Tb[0], Tb[1]), max(Tb[2], Tb[3]));

    // init z slices + record m=0 states
    float zreg[4] = {0, 0, 0, 0};
    if (p3 == 0) {
        #pragma unroll
        for (int b = 0; b < 4; ++b) {
            float z0 = usert[(size_t)u[b] * 128 + gcol];
            zreg[b] = z0;
            zg[b * 128 + gcol] = z0;
        }
    }
    __syncthreads();
    int lp[4] = {0, 0, 0, 0};
    #pragma unroll
    for (int b = 0; b < 4; ++b) {
        while (lp[b] < 128 && sidx_sh[b * 128 + lp[b]] == 0) {
            if (p3 == 0) out[(size_t)b * OS + 2 + (size_t)lp[b] * 128 + gcol] = zreg[b];
            ++lp[b];
        }
    }
    int phase = 0;
    gbar(cnt, ++phase);     // publish z init

    const int c16 = tid >> 4;   // 0..15  (L1/L2 col within slice)
    const int p16 = tid & 15;   // 0..15  (row group)

    for (int t = 0; t < maxT; ++t) {
        float hdt[4]; int si[4];
        #pragma unroll
        for (int b = 0; b < 4; ++b) {
            bool act = (t < Tb[b]);
            hdt[b] = act ? dtsch[b * MAX_T + t] * 0.5f : 0.0f;   // dt / NSUB
            si[b]  = act ? envid[b * MAX_T + t] : 0;
        }
        for (int sub = 0; sub < NSUB; ++sub) {
            // stage x = [z | env] for 4 batches
            for (int idx = tid; idx < 1024; idx += 256) {
                int b = idx >> 8, i = idx & 255;
                float v = (i < 128) ? zg[b * 128 + i]
                                    : envs[((size_t)b * MAX_SEG + si[b]) * 128 + (i - 128)];
                stage[b * 512 + i] = v;
            }
            __syncthreads();
            // ---- layer 1: 256 -> 512 (slice of 16 cols, 4 batches) ----
            {
                float a[4] = {0, 0, 0, 0};
                const float* wrow = w1s + c16 * 256;
                #pragma unroll
                for (int k = 0; k < 4; ++k) {
                    int q = (p16 * 4 + k) * 4;          // dword offset, multiple of 4
                    float4 w = *(const float4*)(wrow + q);
                    #pragma unroll
                    for (int b = 0; b < 4; ++b) {
                        float4 x = *(const float4*)(stage + b * 512 + q);
                        a[b] += w.x * x.x + w.y * x.y + w.z * x.z + w.w * x.w;
                    }
                }
                #pragma unroll
                for (int b = 0; b < 4; ++b)
                    for (int m = 1; m < 16; m <<= 1) a[b] += __shfl_xor(a[b], m, 64);
                if (p16 == 0) {
                    float bb = vb1[g * 16 + c16];
                    #pragma unroll
                    for (int b = 0; b < 4; ++b)
                        h1g[b * 512 + g * 16 + c16] = softplusf(a[b] + bb);
                }
            }
            gbar(cnt, ++phase);     // A: h1 complete
            for (int v = tid; v < 512; v += 256)
                ((float4*)stage)[v] = ((const float4*)h1g)[v];
            __syncthreads();
            // ---- layer 2: 512 -> 512 ----
            {
                float a[4] = {0, 0, 0, 0};
                const float* wrow = w2s + c16 * 512;
                #pragma unroll
                for (int k = 0; k < 8; ++k) {
                    int q = (p16 * 8 + k) * 4;          // 0..511
                    float4 w = *(const float4*)(wrow + q);
                    #pragma unroll
                    for (int b = 0; b < 4; ++b) {
                        float4 x = *(const float4*)(stage + b * 512 + q);
                        a[b] += w.x * x.x + w.y * x.y + w.z * x.z + w.w * x.w;
                    }
                }
                #pragma unroll
                for (int b = 0; b < 4; ++b)
                    for (int m = 1; m < 16; m <<= 1) a[b] += __shfl_xor(a[b], m, 64);
                if (p16 == 0) {
                    float bb = vb2[g * 16 + c16];
                    #pragma unroll
                    for (int b = 0; b < 4; ++b)
                        h2g[b * 512 + g * 16 + c16] = softplusf(a[b] + bb);
                }
            }
            gbar(cnt, ++phase);     // B: h2 complete
            for (int v = tid; v < 512; v += 256)
                ((float4*)stage)[v] = ((const float4*)h2g)[v];
            __syncthreads();
            // ---- layer 3: 512 -> 128 + Euler update (slice of 4 cols) ----
            {
                float a[4] = {0, 0, 0, 0};
                #pragma unroll
                for (int k = 0; k < 2; ++k) {
                    int q = (p3 * 2 + k) * 4;           // 0..511
                    #pragma unroll
                    for (int b = 0; b < 4; ++b) {
                        float4 x = *(const float4*)(stage + b * 512 + q);
                        a[b] += w3r[k * 4 + 0] * x.x + w3r[k * 4 + 1] * x.y
                              + w3r[k * 4 + 2] * x.z + w3r[k * 4 + 3] * x.w;
                    }
                }
                #pragma unroll
                for (int b = 0; b < 4; ++b)
                    for (int m = 1; m < 64; m <<= 1) a[b] += __shfl_xor(a[b], m, 64);
                if (p3 == 0) {
                    float bb = vb3[gcol];
                    #pragma unroll
                    for (int b = 0; b < 4; ++b) {
                        zreg[b] = zreg[b] + hdt[b] * (a[b] + bb);
                        zg[b * 128 + gcol] = zreg[b];
                    }
                }
            }
            gbar(cnt, ++phase);     // C: z complete
        }
        // record states at grid index m = t+1
        int m = t + 1;
        #pragma unroll
        for (int b = 0; b < 4; ++b) {
            while (lp[b] < 128 && sidx_sh[b * 128 + lp[b]] == m) {
                if (p3 == 0) out[(size_t)b * OS + 2 + (size_t)lp[b] * 128 + gcol] = zreg[b];
                ++lp[b];
            }
        }
    }
    // epilogue: scores (WG 0 only; zg is globally consistent after last barrier)
    if (g == 0) {
        int b = tid >> 6, lane = tid & 63;
        const float* zrow = zg + b * 128;
        const float* ep = emb + (size_t)pos[b] * 128;
        const float* en = emb + (size_t)neg[b] * 128;
        float zp = 0.0f, zn = 0.0f;
        for (int i = lane; i < 128; i += 64) {
            float zv = zrow[i];
            zp += zv * ep[i];
            zn += zv * en[i];
        }
        for (int m = 1; m < 64; m <<= 1) { zp += __shfl_xor(zp, m, 64); zn += __shfl_xor(zn, m, 64); }
        if (lane == 0) { out[(size_t)b * OS + 0] = zp; out[(size_t)b * OS + 1] = zn; }
    }
}

extern "C" void kernel_launch(void* const* d_in, const int* in_sizes, int n_in,
                              void* d_out, int out_size, void* d_ws, size_t ws_size,
                              hipStream_t stream) {
    const float* emb   = (const float*)d_in[0];
    const float* w1    = (const float*)d_in[1];
    const float* b1    = (const float*)d_in[2];
    const float* w2    = (const float*)d_in[3];
    const float* b2    = (const float*)d_in[4];
    const float* usert = (const float*)d_in[5];
    const float* vw1   = (const float*)d_in[6];
    const float* vb1   = (const float*)d_in[7];
    const float* vw2   = (const float*)d_in[8];
    const float* vb2   = (const float*)d_in[9];
    const float* vw3   = (const float*)d_in[10];
    const float* vb3   = (const float*)d_in[11];
    const int*   u     = (const int*)d_in[12];
    const int*   hi    = (const int*)d_in[13];
    const float* ht    = (const float*)d_in[14];
    const int*   hl    = (const int*)d_in[15];
    const int*   pos   = (const int*)d_in[16];
    const int*   neg   = (const int*)d_in[17];
    const float* pt    = (const float*)d_in[18];

    int D = in_sizes[2];         // 128
    int B = in_sizes[12];        // 4
    int L = in_sizes[13] / B;    // 128

    // workspace carve-up
    int*   cnt      = (int*)d_ws;                          // 16 ints (barrier)
    float* zgbuf    = (float*)d_ws + 16;                   // 4*128
    float* h1g      = zgbuf + 512;                         // 4*512
    float* h2g      = h1g + 2048;                          // 4*512
    float* enc      = h2g + 2048;                          // B*L*D
    float* envsb    = enc + (size_t)B * L * D;             // B*MAX_SEG*D
    float* dt_sched = envsb + (size_t)B * MAX_SEG * D;     // B*MAX_T
    int*   envid    = (int*)(dt_sched + (size_t)B * MAX_T);// B*MAX_T
    int*   stateidx = envid + (size_t)B * MAX_T;           // B*L
    int*   Tcnt     = stateidx + (size_t)B * L;            // B

    hipMemsetAsync(cnt, 0, 64, stream);
    encode_kernel<<<B * L, D, 0, stream>>>(emb, hi, w1, b1, w2, b2, enc, (float*)d_out, B, L, D);
    plan_kernel<<<B, D, 0, stream>>>(enc, ht, hl, pt, envsb, dt_sched, envid, stateidx, Tcnt, B, L, D);
    ode_coop<<<NWG, 256, 0, stream>>>(usert, u, vw1, vb1, vw2, vb2, vw3, vb3, emb, pos, neg,
                                      envsb, dt_sched, envid, stateidx, Tcnt,
                                      zgbuf, h1g, h2g, cnt, (float*)d_out);
}

// Round 3
// 2851.169 us; speedup vs baseline: 3.0682x; 2.2284x over previous
//
#include <hip/hip_runtime.h>
#include <math.h>

#define W_WIN 5
#define NSUB 2
#define MAX_SEG 64
#define MAX_T 256
#define NWGB 8          // workgroups per batch (ODE)

__device__ __forceinline__ float softplusf(float v) {
    // jax.nn.softplus == logaddexp(v, 0) == max(v,0) + log1p(exp(-|v|))
    return fmaxf(v, 0.0f) + log1pf(expf(-fabsf(v)));
}

// ---------------- wave-level numpy-faithful reductions (plan kernel) ----------------
// lane l holds e0 = a[l], e1 = a[l+64]. numpy pairwise sum for n=128:
// r_k = serial fold a[k]+a[k+8]+...+a[k+120]; then ((r0+r1)+(r2+r3))+((r4+r5)+(r6+r7)).
__device__ __forceinline__ float npsum128(float e0, float e1) {
    int lane = threadIdx.x & 63;
    int k = lane & 7;
    float r = __shfl(e0, k, 64);
    #pragma unroll
    for (int m = 1; m < 8; ++m) r += __shfl(e0, k + 8 * m, 64);
    #pragma unroll
    for (int m = 0; m < 8; ++m) r += __shfl(e1, k + 8 * m, 64);
    float r0 = __shfl(r, 0, 64), r1 = __shfl(r, 1, 64), r2 = __shfl(r, 2, 64), r3 = __shfl(r, 3, 64);
    float r4 = __shfl(r, 4, 64), r5 = __shfl(r, 5, 64), r6 = __shfl(r, 6, 64), r7 = __shfl(r, 7, 64);
    return ((r0 + r1) + (r2 + r3)) + ((r4 + r5) + (r6 + r7));
}

__device__ __forceinline__ float wmax128(float e0, float e1) {
    float m = fmaxf(e0, e1);        // max is exact regardless of order
    #pragma unroll
    for (int s = 1; s < 64; s <<= 1) m = fmaxf(m, __shfl_xor(m, s, 64));
    return m;
}

// ---------------- kernel 1: encoder (also writes traj_t output block) ----------------
__global__ void encode_kernel(const float* __restrict__ emb, const int* __restrict__ hi,
                              const float* __restrict__ w1, const float* __restrict__ b1,
                              const float* __restrict__ w2, const float* __restrict__ b2,
                              float* __restrict__ enc, float* __restrict__ out,
                              int B, int L, int D) {
    __shared__ float x[128];
    __shared__ float h[128];
    int row = blockIdx.x;           // 0 .. B*L-1
    int j = threadIdx.x;            // 0 .. D-1
    int idx = hi[row];
    x[j] = emb[(size_t)idx * D + j];
    __syncthreads();
    float s = b1[j];
    #pragma unroll 8
    for (int i = 0; i < 128; ++i) s += x[i] * w1[i * 128 + j];
    h[j] = fmaxf(s, 0.0f);
    __syncthreads();
    float o = b2[j];
    #pragma unroll 8
    for (int i = 0; i < 128; ++i) o += h[i] * w2[i * 128 + j];
    enc[(size_t)row * D + j] = o;
    int b = row / L, l = row % L;
    size_t OS = 2 + 2 * (size_t)L * D;
    out[(size_t)b * OS + 2 + (size_t)L * D + (size_t)l * D + j] = o;
}

// ---------------- kernel 2: APT partition + plan building (1 wave / batch) ----------------
__global__ __launch_bounds__(64) void plan_kernel(
        const float* __restrict__ enc_all, const float* __restrict__ ht,
        const int* __restrict__ hl, const float* __restrict__ pt,
        float* __restrict__ envs, float* __restrict__ dt_sched,
        int* __restrict__ envid, int* __restrict__ stateidx,
        int* __restrict__ Tcnt, int B, int L, int D) {
    const int b = blockIdx.x;
    const int lane = threadIdx.x;   // 0..63
    const float* encg = enc_all + (size_t)b * L * D;
    const float* times = ht + (size_t)b * L;

    __shared__ float encs[128 * 128];
    __shared__ double cand[160];
    __shared__ double bounds[40];
    __shared__ int starts[40];
    __shared__ int seg_s[40], seg_e[40];
    __shared__ int m_sh;

    // stage enc[b] into LDS (64 KB)
    for (int v = lane; v < 128 * 128 / 4; v += 64)
        ((float4*)encs)[v] = ((const float4*)encg)[v];
    int n = hl[b];
    __syncthreads();

    int nb = 1, ns = 1;             // uniform across the wave
    if (lane == 0) { bounds[0] = (double)times[0]; starts[0] = 0; }
    __syncthreads();

    if (n >= 2 * W_WIN) {
        int j = 0;
        while (j <= n - 2 * W_WIN) {
            const float* r = encs + j * 128;
            float ml0 = (((( r[lane]        + r[128 + lane]) + r[256 + lane]) + r[384 + lane]) + r[512 + lane]) / 5.0f;
            float ml1 = (((( r[64 + lane]   + r[192 + lane]) + r[320 + lane]) + r[448 + lane]) + r[576 + lane]) / 5.0f;
            float mr0 = (((( r[640 + lane]  + r[768 + lane]) + r[896 + lane]) + r[1024 + lane]) + r[1152 + lane]) / 5.0f;
            float mr1 = (((( r[704 + lane]  + r[832 + lane]) + r[960 + lane]) + r[1088 + lane]) + r[1216 + lane]) / 5.0f;
            float mxl = wmax128(ml0, ml1), mxr = wmax128(mr0, mr1);
            float a0 = expf(ml0 - mxl), a1 = expf(ml1 - mxl);
            float c0 = expf(mr0 - mxr), c1 = expf(mr1 - mxr);
            float sl = npsum128(a0, a1), sr = npsum128(c0, c1);
            float p0 = a0 / sl + 1e-8f, p1 = a1 / sl + 1e-8f;
            float q0 = c0 / sr + 1e-8f, q1 = c1 / sr + 1e-8f;
            float sp = npsum128(p0, p1), sq = npsum128(q0, q1);
            p0 /= sp; p1 /= sp; q0 /= sq; q1 /= sq;
            float mv0 = 0.5f * (p0 + q0), mv1 = 0.5f * (p1 + q1);
            float t10 = p0 * logf(p0 / mv0), t11 = p1 * logf(p1 / mv1);
            float t20 = q0 * logf(q0 / mv0), t21 = q1 * logf(q1 / mv1);
            float s1 = npsum128(t10, t11), s2 = npsum128(t20, t21);
            float jsd = 0.5f * s1 + 0.5f * s2;
            if (jsd > 0.5f) {
                if (nb < 39 && ns < 39) {
                    if (lane == 0) {
                        bounds[nb] = ((double)times[j + W_WIN - 1] + (double)times[j + W_WIN]) * 0.5;
                        starts[ns] = j + W_WIN;
                    }
                    nb++; ns++;
                }
                j += W_WIN;
            } else {
                j += 1;
            }
        }
    }
    __syncthreads();

    {
        double lastb = bounds[nb - 1];
        if ((double)times[n - 1] > lastb) {
            if (lane == 0) bounds[nb] = (double)times[n - 1];
            nb++;
        }
    }
    if (lane == 0) {
        for (int si = 0; si < ns; ++si) {
            seg_s[si] = starts[si];
            seg_e[si] = (si + 1 < ns) ? (starts[si + 1] - 1) : (n - 1);
        }
    }
    __syncthreads();

    int C = 0;
    for (int si = 0; si < ns; ++si) {
        int s = seg_s[si], e = seg_e[si];
        if (lane == 0) {
            double t0 = bounds[si];
            double t1 = (si + 1 < nb) ? bounds[si + 1] : bounds[nb - 1];
            // linear merge of sorted(set([t0,t1] + in-range times)); times sorted
            int m = 0;
            cand[m++] = t0;
            for (int l = s; l <= e; ++l) {
                double tv = (double)times[l];
                if (tv < t0 || tv > t1) continue;
                if (tv != cand[m - 1]) cand[m++] = tv;
            }
            if (t1 > cand[m - 1]) cand[m++] = t1;
            // _make_increasing (float64, gap 1e-6)
            for (int k = 1; k < m; ++k)
                if (cand[k] - cand[k - 1] < 1e-6) cand[k] = cand[k - 1] + 1e-6;
            m_sh = m;
        }
        __syncthreads();
        int m = m_sh;
        int K = m - 1;
        if (C + K > MAX_T) K = MAX_T - C;
        for (int k = lane; k < K; k += 64) {
            dt_sched[b * MAX_T + C + k] = (float)(cand[k + 1] - cand[k]);
            envid[b * MAX_T + C + k] = si;
        }
        for (int l = s + lane; l <= e; l += 64) {
            double tv = (double)times[l];
            int best = 0;
            double bd = fabs(cand[0] - tv);
            for (int k = 1; k < m; ++k) {
                double dk = fabs(cand[k] - tv);
                if (dk < bd) { bd = dk; best = k; }
            }
            stateidx[b * L + l] = C + best;
        }
        __syncthreads();
        C += K;
    }

    if (lane == 0) {
        double ptv = (double)pt[b];
        if (ptv > bounds[nb - 1] + 1e-6 && C < MAX_T) {
            double a0d = bounds[nb - 1], a1d = ptv;
            if (a1d - a0d < 1e-6) a1d = a0d + 1e-6;
            dt_sched[b * MAX_T + C] = (float)(a1d - a0d);
            envid[b * MAX_T + C] = ns - 1;
            C++;
        }
        Tcnt[b] = C;
    }
    // per-segment env means (2 dims per lane)
    for (int si = 0; si < ns; ++si) {
        int s = seg_s[si], e = seg_e[si];
        float s0 = 0.0f, s1 = 0.0f;
        for (int l = s; l <= e; ++l) {
            s0 += encs[l * 128 + lane];
            s1 += encs[l * 128 + lane + 64];
        }
        float inv = 1.0f / (float)(e - s + 1);
        envs[((size_t)b * MAX_SEG + si) * 128 + lane] = s0 * inv;
        envs[((size_t)b * MAX_SEG + si) * 128 + lane + 64] = s1 * inv;
    }
}

// ---------------- per-batch flag barrier across NWGB workgroups ----------------
__device__ __forceinline__ void bbar(int* cnt, int* flag, int phase) {
    __syncthreads();
    if (threadIdx.x == 0) {
        __threadfence();    // release: make this WG's stores visible (wbL1/L2)
        int old = __hip_atomic_fetch_add(cnt, 1, __ATOMIC_RELAXED, __HIP_MEMORY_SCOPE_AGENT);
        if (old == phase * NWGB - 1) {
            __hip_atomic_store(flag, phase, __ATOMIC_RELAXED, __HIP_MEMORY_SCOPE_AGENT);
        } else {
            while (__hip_atomic_load(flag, __ATOMIC_RELAXED, __HIP_MEMORY_SCOPE_AGENT) < phase)
                __builtin_amdgcn_s_sleep(1);
        }
        __threadfence();    // acquire: invalidate stale cache lines
    }
    __syncthreads();
}

// ---------------- kernel 3: per-batch cooperative ODE, weights in VGPRs ----------------
// grid = 8*NWGB blocks x 512 thr. batch = blockIdx%8 (exit if >= B), g = blockIdx/8.
// WG g owns h1/h2 cols [g*64,g*64+64) and z cols [g*16,g*16+16).
__global__ __launch_bounds__(512, 1) void ode_coop(
    const float* __restrict__ usert, const int* __restrict__ u,
    const float* __restrict__ vw1, const float* __restrict__ vb1,
    const float* __restrict__ vw2, const float* __restrict__ vb2,
    const float* __restrict__ vw3, const float* __restrict__ vb3,
    const float* __restrict__ emb, const int* __restrict__ pos, const int* __restrict__ neg,
    const float* __restrict__ envs, const float* __restrict__ dtsch,
    const int* __restrict__ envid, const int* __restrict__ stidx,
    const int* __restrict__ Tc,
    float* zg, float* h1g, float* h2g, int* barws,
    float* out, int B)
{
    const int batch = blockIdx.x & 7;
    if (batch >= B) return;
    const int g = blockIdx.x >> 3;      // 0..7
    const int tid = threadIdx.x;        // 0..511

    // L1/L2 mapping: cl = col-in-slice (0..63), q = input-quarter (0..7)
    const int cl = tid >> 3, q = tid & 7;
    const int c12 = g * 64 + cl;
    // L3 mapping: c3l = col-in-slice (0..15), r3 = input-range (0..31)
    const int c3l = tid >> 5, r3 = tid & 31;
    const int c3 = g * 16 + c3l;

    __shared__ float xs[256];
    __shared__ float h1s[512];
    __shared__ float h2s[512];
    __shared__ int sidx_sh[128];

    // ---- preload weight slices into registers, skewed order (static indices!) ----
    float w1r[32], w2r[64], w3r[16];
    #pragma unroll
    for (int k4 = 0; k4 < 8; ++k4) {
        int jj = ((k4 + q) & 7) * 4;
        #pragma unroll
        for (int m = 0; m < 4; ++m)
            w1r[k4 * 4 + m] = vw1[(size_t)(q * 32 + jj + m) * 512 + c12];
    }
    #pragma unroll
    for (int k4 = 0; k4 < 16; ++k4) {
        int jj = ((k4 + 2 * q) & 15) * 4;
        #pragma unroll
        for (int m = 0; m < 4; ++m)
            w2r[k4 * 4 + m] = vw2[(size_t)(q * 64 + jj + m) * 512 + c12];
    }
    #pragma unroll
    for (int k4 = 0; k4 < 4; ++k4) {
        int jj = ((k4 + r3) & 3) * 4;
        #pragma unroll
        for (int m = 0; m < 4; ++m)
            w3r[k4 * 4 + m] = vw3[(size_t)(r3 * 16 + jj + m) * 128 + c3];
    }
    const float bias1 = vb1[c12];
    const float bias2 = vb2[c12];
    const float bias3 = vb3[c3];

    if (tid < 128) sidx_sh[tid] = stidx[batch * 128 + tid];
    __syncthreads();

    const int T = Tc[batch];
    float* zgb  = zg  + batch * 128;
    float* h1gb = h1g + batch * 512;
    float* h2gb = h2g + batch * 512;
    int* cntb  = barws + batch * 64;
    int* flagb = cntb + 16;
    const size_t OS = 2 + 2 * (size_t)128 * 128;
    float* outb = out + (size_t)batch * OS;

    // init z + m=0 records (g==0 writes; others just advance lp)
    int lp = 0;
    if (g == 0 && tid < 128) {
        float z0 = usert[(size_t)u[batch] * 128 + tid];
        zgb[tid] = z0;
        int l = 0;
        while (l < 128 && sidx_sh[l] == 0) { outb[2 + (size_t)l * 128 + tid] = z0; ++l; }
    }
    while (lp < 128 && sidx_sh[lp] == 0) ++lp;
    int phase = 0;
    bbar(cntb, flagb, ++phase);     // publish z0

    for (int t = 0; t < T; ++t) {
        const int si = envid[batch * MAX_T + t];
        const float hdt = dtsch[batch * MAX_T + t] * 0.5f;      // dt / NSUB
        const float* envp = envs + ((size_t)batch * MAX_SEG + si) * 128;
        float zn = 0.0f;
        #pragma unroll
        for (int sub = 0; sub < NSUB; ++sub) {
            // stage x = [z | env]
            if (tid < 128) xs[tid] = zgb[tid];
            else if (tid < 256) xs[tid] = envp[tid - 128];
            __syncthreads();
            // ---- layer 1: 256 -> 512, partials over q, reduce 8 lanes ----
            float acc = 0.0f;
            #pragma unroll
            for (int k4 = 0; k4 < 8; ++k4) {
                int off = q * 32 + ((k4 + q) & 7) * 4;
                float4 xv = *(const float4*)(xs + off);
                acc += w1r[k4 * 4 + 0] * xv.x + w1r[k4 * 4 + 1] * xv.y
                     + w1r[k4 * 4 + 2] * xv.z + w1r[k4 * 4 + 3] * xv.w;
            }
            #pragma unroll
            for (int s = 1; s < 8; s <<= 1) acc += __shfl_xor(acc, s, 64);
            if (q == 0) h1gb[c12] = softplusf(acc + bias1);
            bbar(cntb, flagb, ++phase);     // h1 complete
            h1s[tid] = h1gb[tid];
            __syncthreads();
            // ---- layer 2: 512 -> 512 ----
            acc = 0.0f;
            #pragma unroll
            for (int k4 = 0; k4 < 16; ++k4) {
                int off = q * 64 + ((k4 + 2 * q) & 15) * 4;
                float4 xv = *(const float4*)(h1s + off);
                acc += w2r[k4 * 4 + 0] * xv.x + w2r[k4 * 4 + 1] * xv.y
                     + w2r[k4 * 4 + 2] * xv.z + w2r[k4 * 4 + 3] * xv.w;
            }
            #pragma unroll
            for (int s = 1; s < 8; s <<= 1) acc += __shfl_xor(acc, s, 64);
            if (q == 0) h2gb[c12] = softplusf(acc + bias2);
            bbar(cntb, flagb, ++phase);     // h2 complete
            h2s[tid] = h2gb[tid];
            __syncthreads();
            // ---- layer 3: 512 -> 128 + Euler update ----
            acc = 0.0f;
            #pragma unroll
            for (int k4 = 0; k4 < 4; ++k4) {
                int off = r3 * 16 + ((k4 + r3) & 3) * 4;
                float4 xv = *(const float4*)(h2s + off);
                acc += w3r[k4 * 4 + 0] * xv.x + w3r[k4 * 4 + 1] * xv.y
                     + w3r[k4 * 4 + 2] * xv.z + w3r[k4 * 4 + 3] * xv.w;
            }
            #pragma unroll
            for (int s = 1; s < 32; s <<= 1) acc += __shfl_xor(acc, s, 64);
            zn = xs[c3] + hdt * (acc + bias3);
            if (r3 == 0) zgb[c3] = zn;
            bbar(cntb, flagb, ++phase);     // z complete
        }
        // record states at grid index m = t+1 (each WG writes its 16 z cols)
        const int m = t + 1;
        while (lp < 128 && sidx_sh[lp] == m) {
            if (r3 == 0) outb[2 + (size_t)lp * 128 + c3] = zn;
            ++lp;
        }
    }
    // epilogue: scores (g==0; zgb fresh after final barrier's acquire)
    if (g == 0 && tid < 128) {
        int lane = tid & 63;
        const int item = (tid < 64) ? pos[batch] : neg[batch];
        const float* ev = emb + (size_t)item * 128;
        float sacc = zgb[lane] * ev[lane] + zgb[lane + 64] * ev[lane + 64];
        #pragma unroll
        for (int s = 1; s < 64; s <<= 1) sacc += __shfl_xor(sacc, s, 64);
        if (lane == 0) outb[(tid < 64) ? 0 : 1] = sacc;
    }
}

extern "C" void kernel_launch(void* const* d_in, const int* in_sizes, int n_in,
                              void* d_out, int out_size, void* d_ws, size_t ws_size,
                              hipStream_t stream) {
    const float* emb   = (const float*)d_in[0];
    const float* w1    = (const float*)d_in[1];
    const float* b1    = (const float*)d_in[2];
    const float* w2    = (const float*)d_in[3];
    const float* b2    = (const float*)d_in[4];
    const float* usert = (const float*)d_in[5];
    const float* vw1   = (const float*)d_in[6];
    const float* vb1   = (const float*)d_in[7];
    const float* vw2   = (const float*)d_in[8];
    const float* vb2   = (const float*)d_in[9];
    const float* vw3   = (const float*)d_in[10];
    const float* vb3   = (const float*)d_in[11];
    const int*   u     = (const int*)d_in[12];
    const int*   hi    = (const int*)d_in[13];
    const float* ht    = (const float*)d_in[14];
    const int*   hl    = (const int*)d_in[15];
    const int*   pos   = (const int*)d_in[16];
    const int*   neg   = (const int*)d_in[17];
    const float* pt    = (const float*)d_in[18];

    int D = in_sizes[2];         // 128
    int B = in_sizes[12];        // 4
    int L = in_sizes[13] / B;    // 128

    // workspace carve-up (barrier region first, 16B-aligned buffers after)
    int*   barws    = (int*)d_ws;                           // 4 batches x 256 B
    float* zgbuf    = (float*)((char*)d_ws + 4096);         // B*128
    float* h1g      = zgbuf + 512;                          // B*512
    float* h2g      = h1g + 2048;                           // B*512
    float* enc      = h2g + 2048;                           // B*L*D
    float* envsb    = enc + (size_t)B * L * D;              // B*MAX_SEG*D
    float* dt_sched = envsb + (size_t)B * MAX_SEG * D;      // B*MAX_T
    int*   envid    = (int*)(dt_sched + (size_t)B * MAX_T); // B*MAX_T
    int*   stateidx = envid + (size_t)B * MAX_T;            // B*L
    int*   Tcnt     = stateidx + (size_t)B * L;             // B

    hipMemsetAsync(barws, 0, 4096, stream);
    encode_kernel<<<B * L, D, 0, stream>>>(emb, hi, w1, b1, w2, b2, enc, (float*)d_out, B, L, D);
    plan_kernel<<<B, 64, 0, stream>>>(enc, ht, hl, pt, envsb, dt_sched, envid, stateidx, Tcnt, B, L, D);
    ode_coop<<<8 * NWGB, 512, 0, stream>>>(usert, u, vw1, vb1, vw2, vb2, vw3, vb3, emb, pos, neg,
                                           envsb, dt_sched, envid, stateidx, Tcnt,
                                           zgbuf, h1g, h2g, barws, (float*)d_out, B);
}